// Round 2
// baseline (188.683 us; speedup 1.0000x reference)
//
#include <hip/hip_runtime.h>

typedef unsigned short u16;
typedef __attribute__((ext_vector_type(8))) short short8;
typedef __attribute__((ext_vector_type(4))) float f32x4;

#define X0    (-6.0f)
#define GH    (12.0f / 256.0f)     // grid spacing h = 0.046875
#define LOG2E 1.44269504089f

__device__ __forceinline__ u16 f2bf(float x) {
    union { float f; unsigned int u; } v; v.f = x;
    unsigned int r = (v.u + 0x7fffu + ((v.u >> 16) & 1u)) >> 16;
    return (u16)r;
}
__device__ __forceinline__ unsigned int pk(u16 a, u16 b) {
    return (unsigned int)a | ((unsigned int)b << 16);
}

// 1024 blocks: (chunk 0..3) x (b 0..3) x (v8 0..63). Each bins 1024 keys for
// 8 v-rows into LDS fp32 histogram, flushes to Hpart[chunk][b*512+v][j] fp32.
__global__ __launch_bounds__(256) void bin_kernel(
    const float* __restrict__ key, const float* __restrict__ value,
    float* __restrict__ Hpart)
{
    __shared__ int   jj[1024];
    __shared__ float ff[1024];
    __shared__ float Hl[256 * 9];   // [256 bins][8 v] stride 9

    const int tid   = threadIdx.x;
    const int chunk = blockIdx.x >> 8;
    const int rem   = blockIdx.x & 255;
    const int b     = rem >> 6;
    const int v0    = (rem & 63) << 3;
    const int sbase = chunk << 10;

    for (int i = tid; i < 256 * 9; i += 256) Hl[i] = 0.0f;
    const float inv_h = 256.0f / 12.0f;
    for (int r = 0; r < 4; ++r) {
        int s = tid + (r << 8);
        float k = key[b * 4096 + sbase + s];
        float u = (k - X0) * inv_h;
        int j = (int)floorf(u);
        j = j < 0 ? 0 : (j > 254 ? 254 : j);
        float f = u - (float)j;
        f = f < 0.0f ? 0.0f : (f > 1.0f ? 1.0f : f);
        jj[s] = j; ff[s] = f;
    }
    __syncthreads();

    const int vloc = tid >> 5, slane = tid & 31;
    const float* vrow = value + (size_t)(b * 512 + v0 + vloc) * 4096 + sbase;
    for (int c = 0; c < 8; ++c) {
        int s = (slane << 2) + (c << 7);
        float4 val = *(const float4*)(vrow + s);
        int4   j4  = *(const int4*)(&jj[s]);
        float4 f4  = *(const float4*)(&ff[s]);
        atomicAdd(&Hl[ j4.x      * 9 + vloc], val.x * (1.0f - f4.x));
        atomicAdd(&Hl[(j4.x + 1) * 9 + vloc], val.x * f4.x);
        atomicAdd(&Hl[ j4.y      * 9 + vloc], val.y * (1.0f - f4.y));
        atomicAdd(&Hl[(j4.y + 1) * 9 + vloc], val.y * f4.y);
        atomicAdd(&Hl[ j4.z      * 9 + vloc], val.z * (1.0f - f4.z));
        atomicAdd(&Hl[(j4.z + 1) * 9 + vloc], val.z * f4.z);
        atomicAdd(&Hl[ j4.w      * 9 + vloc], val.w * (1.0f - f4.w));
        atomicAdd(&Hl[(j4.w + 1) * 9 + vloc], val.w * f4.w);
    }
    __syncthreads();

    float* base = Hpart + ((size_t)chunk * 2048 + b * 512 + v0) * 256;
    for (int r = 0; r < 8; ++r)          // row r = v-local, col tid = bin j
        base[(r << 8) + tid] = Hl[tid * 9 + r];
}

// Sum 4 fp32 partials -> bf16 H[b*512+v][j]. 512 blocks x 256 thr x 4 j.
__global__ __launch_bounds__(256) void reduce_kernel(
    const float* __restrict__ Hpart, u16* __restrict__ Hbf)
{
    const int gid = blockIdx.x * 256 + threadIdx.x;   // 0..131071 (float4 units)
    const float4* p = (const float4*)Hpart;
    float4 s0 = p[gid];
    float4 s1 = p[gid + 131072];
    float4 s2 = p[gid + 262144];
    float4 s3 = p[gid + 393216];
    float sx = s0.x + s1.x + s2.x + s3.x;
    float sy = s0.y + s1.y + s2.y + s3.y;
    float sz = s0.z + s1.z + s2.z + s3.z;
    float sw = s0.w + s1.w + s2.w + s3.w;
    uint2 o = make_uint2(pk(f2bf(sx), f2bf(sy)), pk(f2bf(sz), f2bf(sw)));
    *(uint2*)(Hbf + (size_t)gid * 4) = o;
}

// out[b][t][v] = sum_k G(q_t, x_k) * H[v][k].
// MFMA 16x16x32_bf16: A-operand = H (M=v=128/block, staged in LDS),
// B-operand = Gaussian computed on the fly in registers (N=t=128/block).
// C mapping: row(quad*4+reg)=v (A's m-index), col(lane&15)=t (B's n-index)
// -> lane holds 4 consecutive v at fixed t -> dwordx4 stores.
__global__ __launch_bounds__(256) void gemm_kernel(
    const float* __restrict__ query, const float* __restrict__ log_scale,
    const u16* __restrict__ Hbf, float* __restrict__ out)
{
    __shared__ u16 Hl[128 * 40];   // 128 v-rows x 32 k, stride 40 shorts

    const int tid  = threadIdx.x;
    const int v0   = blockIdx.x << 7;
    const int t0   = blockIdx.y << 7;
    const int b    = blockIdx.z;
    const int lane = tid & 63;
    const int wave = tid >> 6;
    const int wv   = (wave & 1) << 6;    // v-half of tile (M)
    const int wt   = (wave >> 1) << 6;   // t-half of tile (N)
    const int m15  = lane & 15;
    const int kq   = lane >> 4;          // quad 0..3

    const float c2 = -0.5f * LOG2E * exp2f(-2.0f * LOG2E * log_scale[0]);
    float q[4];
    for (int ni = 0; ni < 4; ++ni)
        q[ni] = query[b * 4096 + t0 + wt + ni * 16 + m15];

    f32x4 acc[4][4];
    for (int i = 0; i < 4; ++i)
        for (int j = 0; j < 4; ++j)
            acc[i][j] = (f32x4){0.f, 0.f, 0.f, 0.f};

    const int srow  = tid >> 1;
    const int spart = (tid & 1) << 4;
    const u16* Hg = Hbf + (size_t)(b * 512 + v0 + srow) * 256 + spart;
    u16* Hw = Hl + srow * 40 + spart;

    for (int ks = 0; ks < 8; ++ks) {
        const int k0 = ks << 5;
        uint4 h0 = *(const uint4*)(Hg + k0);
        uint4 h1 = *(const uint4*)(Hg + k0 + 8);
        __syncthreads();
        *(uint4*)(Hw)     = h0;
        *(uint4*)(Hw + 8) = h1;
        __syncthreads();

        short8 af[4];
        for (int i = 0; i < 4; ++i)
            af[i] = *(const short8*)(Hl + (wv + i * 16 + m15) * 40 + kq * 8);

        short8 bfr[4];
        const float xb = X0 + GH * (float)(k0 + kq * 8);
        for (int ni = 0; ni < 4; ++ni) {
            short8 e;
            for (int j = 0; j < 8; ++j) {
                float d = q[ni] - (xb + GH * (float)j);
                e[j] = (short)f2bf(exp2f(c2 * d * d));
            }
            bfr[ni] = e;
        }

        for (int mi = 0; mi < 4; ++mi)
            for (int ni = 0; ni < 4; ++ni)
                acc[mi][ni] = __builtin_amdgcn_mfma_f32_16x16x32_bf16(
                    af[mi], bfr[ni], acc[mi][ni], 0, 0, 0);
    }

    for (int mi = 0; mi < 4; ++mi) {
        for (int ni = 0; ni < 4; ++ni) {
            int t = t0 + wt + ni * 16 + m15;
            float* o = out + (size_t)(b * 4096 + t) * 512
                           + v0 + wv + mi * 16 + (kq << 2);
            *(f32x4*)o = acc[mi][ni];
        }
    }
}

extern "C" void kernel_launch(void* const* d_in, const int* in_sizes, int n_in,
                              void* d_out, int out_size, void* d_ws, size_t ws_size,
                              hipStream_t stream)
{
    const float* query = (const float*)d_in[0];   // [4,4096,1]
    const float* key   = (const float*)d_in[1];   // [4,4096,1]
    const float* value = (const float*)d_in[2];   // [4,512,4096]
    const float* lsc   = (const float*)d_in[3];   // scalar
    float* out = (float*)d_out;                   // [4,4096,512]

    float* Hpart = (float*)d_ws;                  // [4][2048][256] fp32 = 8 MB
    u16*   Hbf   = (u16*)((char*)d_ws + (size_t)8 * 1024 * 1024);  // 1 MB

    bin_kernel<<<1024, 256, 0, stream>>>(key, value, Hpart);
    reduce_kernel<<<512, 256, 0, stream>>>(Hpart, Hbf);
    gemm_kernel<<<dim3(4, 32, 4), 256, 0, stream>>>(query, lsc, Hbf, out);
}

// Round 3
// 143.729 us; speedup vs baseline: 1.3128x; 1.3128x over previous
//
#include <hip/hip_runtime.h>

typedef unsigned short u16;
typedef __attribute__((ext_vector_type(8))) short short8;
typedef __attribute__((ext_vector_type(4))) float f32x4;

#define X0    (-6.0f)
#define GH    (12.0f / 256.0f)     // grid spacing h = 0.046875
#define LOG2E 1.44269504089f

__device__ __forceinline__ u16 f2bf(float x) {
    union { float f; unsigned int u; } v; v.f = x;
    unsigned int r = (v.u + 0x7fffu + ((v.u >> 16) & 1u)) >> 16;
    return (u16)r;
}
__device__ __forceinline__ unsigned int pk(u16 a, u16 b) {
    return (unsigned int)a | ((unsigned int)b << 16);
}
__device__ __forceinline__ short8 cvt8(float4 lo, float4 hi) {
    union { short8 s; uint4 u; } r;
    r.u = make_uint4(pk(f2bf(lo.x), f2bf(lo.y)), pk(f2bf(lo.z), f2bf(lo.w)),
                     pk(f2bf(hi.x), f2bf(hi.y)), pk(f2bf(hi.z), f2bf(hi.w)));
    return r.s;
}

// K1: build dense CIC matrix Wt[b][j][s] bf16 (4x256x4096 = 8MB) and zero Hf32.
// Block = (b, 64-key s-chunk); thread t owns bin-row j=t. Pure selects, no atomics.
__global__ __launch_bounds__(256) void wbuild_kernel(
    const float* __restrict__ key, u16* __restrict__ Wt, float* __restrict__ Hf)
{
    __shared__ int   jl[64];
    __shared__ float fl[64];
    const int tid = threadIdx.x;
    const int b   = blockIdx.x >> 6;
    const int s0  = (blockIdx.x & 63) << 6;

    if (tid < 64) {
        float k = key[b * 4096 + s0 + tid];
        float u = (k - X0) * (256.0f / 12.0f);
        int j = (int)floorf(u);
        j = j < 0 ? 0 : (j > 254 ? 254 : j);
        float f = u - (float)j;
        f = f < 0.0f ? 0.0f : (f > 1.0f ? 1.0f : f);
        jl[tid] = j; fl[tid] = f;
    }
    {   // zero Hf32: 524288 floats / 65536 threads = 8 each
        float4 z = make_float4(0.f, 0.f, 0.f, 0.f);
        float* p = Hf + ((size_t)blockIdx.x * 256 + tid) * 8;
        *(float4*)p = z; *(float4*)(p + 4) = z;
    }
    __syncthreads();

    u16 e[64];
    #pragma unroll
    for (int i = 0; i < 64; ++i) {
        int j = jl[i]; float f = fl[i];
        float w = (j == tid) ? (1.0f - f) : ((j + 1 == tid) ? f : 0.0f);
        e[i] = f2bf(w);
    }
    u16* row = Wt + ((size_t)(b * 256 + tid)) * 4096 + s0;
    #pragma unroll
    for (int r = 0; r < 8; ++r) {
        uint4 o = make_uint4(pk(e[r*8+0], e[r*8+1]), pk(e[r*8+2], e[r*8+3]),
                             pk(e[r*8+4], e[r*8+5]), pk(e[r*8+6], e[r*8+7]));
        *(uint4*)(row + r * 8) = o;
    }
}

// K2: H[v][j] = sum_s value[v][s] * Wt[j][s].  MFMA bf16, M=512 N=256 K=4096,
// 8-way k-split, fp32 global atomicAdd accumulate. No LDS at all.
__global__ __launch_bounds__(256) void hgemm_kernel(
    const float* __restrict__ value, const u16* __restrict__ Wt,
    float* __restrict__ Hf)
{
    const int tid  = threadIdx.x;
    const int j0   = blockIdx.x << 7;          // 0,128
    const int v0   = blockIdx.y << 7;          // 0..384
    const int b    = blockIdx.z >> 3;
    const int ks   = blockIdx.z & 7;
    const int kbase = ks << 9;                 // 512-wide K chunk
    const int lane = tid & 63;
    const int wave = tid >> 6;
    const int wv   = (wave & 1) << 6;
    const int wj   = (wave >> 1) << 6;
    const int m15  = lane & 15;
    const int kq   = lane >> 4;

    f32x4 acc[4][4];
    for (int i = 0; i < 4; ++i)
        for (int j = 0; j < 4; ++j)
            acc[i][j] = (f32x4){0.f, 0.f, 0.f, 0.f};

    const float* ap[4];
    const u16*   bp[4];
    for (int i = 0; i < 4; ++i) {
        ap[i] = value + (size_t)(b * 512 + v0 + wv + i * 16 + m15) * 4096 + kbase + kq * 8;
        bp[i] = Wt    + (size_t)(b * 256 + j0 + wj + i * 16 + m15) * 4096 + kbase + kq * 8;
    }

    for (int kk = 0; kk < 16; ++kk) {
        const int ko = kk << 5;
        short8 af[4], bf[4];
        for (int i = 0; i < 4; ++i) {
            float4 lo = *(const float4*)(ap[i] + ko);
            float4 hi = *(const float4*)(ap[i] + ko + 4);
            af[i] = cvt8(lo, hi);
            union { short8 s; uint4 u; } w;
            w.u = *(const uint4*)(bp[i] + ko);
            bf[i] = w.s;
        }
        for (int mi = 0; mi < 4; ++mi)
            for (int ni = 0; ni < 4; ++ni)
                acc[mi][ni] = __builtin_amdgcn_mfma_f32_16x16x32_bf16(
                    af[mi], bf[ni], acc[mi][ni], 0, 0, 0);
    }

    for (int mi = 0; mi < 4; ++mi) {
        for (int ni = 0; ni < 4; ++ni) {
            float* base = Hf + ((size_t)(b * 512 + v0 + wv + mi * 16 + (kq << 2))) * 256
                             + j0 + wj + ni * 16 + m15;
            for (int r = 0; r < 4; ++r)
                atomicAdd(base + (size_t)r * 256, acc[mi][ni][r]);
        }
    }
}

// K3: out[b][t][v] = sum_k G(q_t, x_k) * H[v][k].
// Whole H-tile (128 v x 256 k) staged in dynamic LDS ONCE -> single barrier,
// then 8 barrier-free MFMA steps with on-the-fly Gaussian B-fragments.
__global__ __launch_bounds__(256) void gemm_kernel(
    const float* __restrict__ query, const float* __restrict__ log_scale,
    const float* __restrict__ Hf, float* __restrict__ out)
{
    extern __shared__ u16 Hl[];        // 128 rows x 264 stride = 67584 B

    const int tid  = threadIdx.x;
    const int v0   = blockIdx.x << 7;
    const int t0   = blockIdx.y << 7;
    const int b    = blockIdx.z;
    const int lane = tid & 63;
    const int wave = tid >> 6;
    const int wv   = (wave & 1) << 6;
    const int wt   = (wave >> 1) << 6;
    const int m15  = lane & 15;
    const int kq   = lane >> 4;

    const float c2 = -0.5f * LOG2E * exp2f(-2.0f * LOG2E * log_scale[0]);
    float q[4];
    for (int ni = 0; ni < 4; ++ni)
        q[ni] = query[b * 4096 + t0 + wt + ni * 16 + m15];

    // stage: thread = (row = tid>>1, half = tid&1) -> 128 fp32 -> 128 bf16
    {
        const int row = tid >> 1, half = tid & 1;
        const float* src = Hf + (size_t)(b * 512 + v0 + row) * 256 + half * 128;
        u16* dst = Hl + row * 264 + half * 128;
        #pragma unroll
        for (int kk = 0; kk < 8; ++kk) {
            float4 x0 = *(const float4*)(src + kk * 16);
            float4 x1 = *(const float4*)(src + kk * 16 + 4);
            float4 x2 = *(const float4*)(src + kk * 16 + 8);
            float4 x3 = *(const float4*)(src + kk * 16 + 12);
            union { short8 s; uint4 u; } o0, o1;
            o0.s = cvt8(x0, x1); o1.s = cvt8(x2, x3);
            *(uint4*)(dst + kk * 16)     = o0.u;
            *(uint4*)(dst + kk * 16 + 8) = o1.u;
        }
    }
    __syncthreads();

    f32x4 acc[4][4];
    for (int i = 0; i < 4; ++i)
        for (int j = 0; j < 4; ++j)
            acc[i][j] = (f32x4){0.f, 0.f, 0.f, 0.f};

    for (int ks = 0; ks < 8; ++ks) {
        const int k0 = ks << 5;
        short8 af[4];
        for (int i = 0; i < 4; ++i)
            af[i] = *(const short8*)(Hl + (wv + i * 16 + m15) * 264 + k0 + kq * 8);

        short8 bfr[4];
        const float xb = X0 + GH * (float)(k0 + kq * 8);
        for (int ni = 0; ni < 4; ++ni) {
            short8 e;
            for (int j = 0; j < 8; ++j) {
                float d = q[ni] - (xb + GH * (float)j);
                e[j] = (short)f2bf(exp2f(c2 * d * d));
            }
            bfr[ni] = e;
        }
        for (int mi = 0; mi < 4; ++mi)
            for (int ni = 0; ni < 4; ++ni)
                acc[mi][ni] = __builtin_amdgcn_mfma_f32_16x16x32_bf16(
                    af[mi], bfr[ni], acc[mi][ni], 0, 0, 0);
    }

    for (int mi = 0; mi < 4; ++mi) {
        for (int ni = 0; ni < 4; ++ni) {
            int t = t0 + wt + ni * 16 + m15;
            float* o = out + (size_t)(b * 4096 + t) * 512
                           + v0 + wv + mi * 16 + (kq << 2);
            *(f32x4*)o = acc[mi][ni];
        }
    }
}

extern "C" void kernel_launch(void* const* d_in, const int* in_sizes, int n_in,
                              void* d_out, int out_size, void* d_ws, size_t ws_size,
                              hipStream_t stream)
{
    const float* query = (const float*)d_in[0];   // [4,4096,1]
    const float* key   = (const float*)d_in[1];   // [4,4096,1]
    const float* value = (const float*)d_in[2];   // [4,512,4096]
    const float* lsc   = (const float*)d_in[3];   // scalar
    float* out = (float*)d_out;                   // [4,4096,512]

    u16*   Wt = (u16*)d_ws;                                        // 8 MB
    float* Hf = (float*)((char*)d_ws + (size_t)8 * 1024 * 1024);   // 2 MB

    wbuild_kernel<<<256, 256, 0, stream>>>(key, Wt, Hf);
    hgemm_kernel<<<dim3(2, 4, 32), 256, 0, stream>>>(value, Wt, Hf);
    gemm_kernel<<<dim3(4, 32, 4), 256, 128 * 264 * 2, stream>>>(query, lsc, Hf, out);
}